// Round 8
// baseline (2969.759 us; speedup 1.0000x reference)
//
#include <hip/hip_runtime.h>

// QINCo round 8: MFMA fp16 hi/lo split with PRE-SPLIT weights.
//  - k_wsplit converts W1/W2 (all 7 steps) to scaled fp16 hi/lo in ws once.
//  - k_step inner loop: 2 global b128 (A hi/lo) + 2 LDS b128 (B hi/lo) + 3 MFMA.
//  - LDS: Zh/Zl[64][128] + Hh/Hl[64][64] = 48KB -> 3 blocks/CU.
//  - 8-half rotation: every LDS fragment is one contiguous ds_read_b128.
// Fallback (ws too small): round-7 kernel (on-the-fly split), known-good.
// Shapes: D=128, M=8, K=256, L=2, H=256, BS=1024.
// Out layout (floats): xhat[1024*128] | codes[1024*8] | side[8][1024*128]

typedef _Float16 f16;
typedef f16 half4_t __attribute__((ext_vector_type(4)));
typedef f16 half8_t __attribute__((ext_vector_type(8)));
typedef float f32x16 __attribute__((ext_vector_type(16)));

#define OUT_CODES 131072
#define OUT_SIDE  139264

// ws float offsets
#define WS_XHAT  0          // [1024][128]
#define WS_RB    131072     // [1024][128]  r = x - xhat
#define WS_Y     262144     // [1024][128]  y = xhat @ Wx^T
#define WS_ZC    393216     // [256][128]   zc = cb + cb@Wz^T + bc
#define WS_BESTD 425984     // [1024][4]
#define WS_BESTI 430080     // [1024][4] (int)
#define WS_BESTZ 434176     // [1024][4][128]
#define WS_WSPLIT 960000    // f16 region: W1H|W1L|W2H|W2L, 458752 halfs each
#define NW1 458752          // 7*2*256*128
#define WS_NEED_BYTES (WS_WSPLIT * 4 + 4 * NW1 * 2)

__device__ __forceinline__ f32x16 mfma_f16(half8_t a, half8_t b, f32x16 c) {
  return __builtin_amdgcn_mfma_f32_32x32x16_f16(a, b, c, 0, 0, 0);
}

// ---------------- weight pre-split: fp32 -> scaled (x256) fp16 hi/lo ----------------
__global__ __launch_bounds__(256) void k_wsplit(const float* __restrict__ W1,
    const float* __restrict__ W2, f16* __restrict__ wsh)
{
  int i = (blockIdx.x * 256 + threadIdx.x) * 4;      // [0, 2*NW1)
  const float* src;
  f16* hi;
  if (i < NW1) { src = W1 + i; hi = wsh + i; }
  else         { src = W2 + (i - NW1); hi = wsh + 2 * NW1 + (i - NW1); }
  f16* lo = hi + NW1;
  float4 v = *(const float4*)src;
  half4_t h, l;
  float s;
  s = v.x * 256.f; h[0] = (f16)s; l[0] = (f16)(s - (float)h[0]);
  s = v.y * 256.f; h[1] = (f16)s; l[1] = (f16)(s - (float)h[1]);
  s = v.z * 256.f; h[2] = (f16)s; l[2] = (f16)(s - (float)h[2]);
  s = v.w * 256.f; h[3] = (f16)s; l[3] = (f16)(s - (float)h[3]);
  *(half4_t*)hi = h;
  *(half4_t*)lo = l;
}

// ---------------- step 0: nearest codebook0 row ----------------
__global__ __launch_bounds__(256) void k_step0(const float* __restrict__ x,
    const float* __restrict__ cb0, float* __restrict__ ws, float* __restrict__ out)
{
  __shared__ float xs[128];
  __shared__ float redv[4];
  __shared__ int   redi[4];
  __shared__ int   kwin;
  int tx = threadIdx.x, b = blockIdx.x;
  if (tx < 128) xs[tx] = x[b * 128 + tx];
  __syncthreads();
  const float* c = cb0 + tx * 128;   // k = tx
  float s = 0.f;
  for (int d = 0; d < 128; d += 4) {
    float4 cv = *(const float4*)(c + d);
    float4 xv = *(const float4*)(xs + d);
    float a0 = xv.x - cv.x, a1 = xv.y - cv.y, a2 = xv.z - cv.z, a3 = xv.w - cv.w;
    s += a0 * a0 + a1 * a1 + a2 * a2 + a3 * a3;
  }
  float v = s; int idx = tx;
  for (int off = 32; off; off >>= 1) {
    float v2 = __shfl_xor(v, off);
    int   i2 = __shfl_xor(idx, off);
    if (v2 < v || (v2 == v && i2 < idx)) { v = v2; idx = i2; }
  }
  if ((tx & 63) == 0) { redv[tx >> 6] = v; redi[tx >> 6] = idx; }
  __syncthreads();
  if (tx == 0) {
    float bv = redv[0]; int bi = redi[0];
    for (int w = 1; w < 4; w++)
      if (redv[w] < bv || (redv[w] == bv && redi[w] < bi)) { bv = redv[w]; bi = redi[w]; }
    kwin = bi;
    out[OUT_CODES + b * 8] = (float)bi;
  }
  __syncthreads();
  int k = kwin;
  if (tx < 128) {
    float xh = cb0[k * 128 + tx];
    ws[WS_XHAT + b * 128 + tx] = xh;
    ws[WS_RB   + b * 128 + tx] = xs[tx] - xh;
    out[OUT_SIDE + b * 128 + tx] = xh;   // side[0]
  }
}

// ---------------- per-step prep: zc and y (fp32) ----------------
__global__ __launch_bounds__(128) void k_prep(const float* __restrict__ cb,
    const float* __restrict__ Wc, const float* __restrict__ bcm, float* __restrict__ ws)
{
  __shared__ float row[128];
  int tx = threadIdx.x, blk = blockIdx.x;
  if (blk < 256) {          // zc[k][i] = cb[k][i] + sum_d cb[k][d]*Wc[i][d] + bc[i]
    row[tx] = cb[blk * 128 + tx];
    __syncthreads();
    const float* wrow = Wc + tx * 256;
    float s = 0.f;
    for (int d = 0; d < 128; d += 4) {
      float4 wv = *(const float4*)(wrow + d);
      float4 zv = *(const float4*)(row + d);
      s += wv.x * zv.x + wv.y * zv.y + wv.z * zv.z + wv.w * zv.w;
    }
    ws[WS_ZC + blk * 128 + tx] = row[tx] + s + bcm[tx];
  } else {                  // y[b][i] = sum_d xhat[b][d]*Wc[i][128+d]
    int b = blk - 256;
    row[tx] = ws[WS_XHAT + b * 128 + tx];
    __syncthreads();
    const float* wrow = Wc + tx * 256 + 128;
    float s = 0.f;
    for (int d = 0; d < 128; d += 4) {
      float4 wv = *(const float4*)(wrow + d);
      float4 zv = *(const float4*)(row + d);
      s += wv.x * zv.x + wv.y * zv.y + wv.z * zv.z + wv.w * zv.w;
    }
    ws[WS_Y + b * 128 + tx] = s;
  }
}

// ---------------- main step kernel (pre-split weights) ----------------
// 256 threads = 4 waves. lane: col = lane&31, koct = lane>>5.
// Z LDS: [64 m][128 d] halfs, logical d at phys (d + 8*(m&15)) & 127.
// H LDS (64-wide quarter): [64 m][64 h], logical h at (h + 8*(m&7)) & 63.
// GEMM1 per quarter hq: wave w -> tile (h in [32(w>>1),+32), m in [32(w&1),+32)).
// GEMM2: wave w -> d rows [32w,+32), both m tiles, K accumulated over quarters.
// C/D layout: col=lane&31, row = (reg&3) + 8*(reg>>2) + 4*koct.
__global__ __launch_bounds__(256, 3) void k_step(const f16* __restrict__ wsh,
    float* __restrict__ ws, int sm)
{
  __shared__ f16 Zh[8192];
  __shared__ f16 Zl[8192];
  __shared__ f16 Hh[4096];
  __shared__ f16 Hl[4096];
  int tx = threadIdx.x;
  int lane = tx & 63, w = tx >> 6;
  int col = lane & 31, koct = lane >> 5;
  int b = blockIdx.x >> 2, t = blockIdx.x & 3, k0 = t << 6;

  // ---- init Z = zc[k0+m] + y[b], split x256 into Zh/Zl ----
  {
    const float* zc = ws + WS_ZC + k0 * 128;
    const float* y  = ws + WS_Y + b * 128;
    for (int idx = tx; idx < 1024; idx += 256) {
      int m = idx & 63, d0 = (idx >> 6) << 3;
      float4 a  = *(const float4*)(zc + m * 128 + d0);
      float4 bb = *(const float4*)(zc + m * 128 + d0 + 4);
      float4 ya = *(const float4*)(y + d0);
      float4 yb = *(const float4*)(y + d0 + 4);
      float sv[8] = {a.x + ya.x, a.y + ya.y, a.z + ya.z, a.w + ya.w,
                     bb.x + yb.x, bb.y + yb.y, bb.z + yb.z, bb.w + yb.w};
      half8_t h8, l8;
#pragma unroll
      for (int j = 0; j < 8; j++) {
        float v = sv[j] * 256.f;
        f16 h = (f16)v; h8[j] = h; l8[j] = (f16)(v - (float)h);
      }
      int c0 = (d0 + ((m & 15) << 3)) & 127;
      *(half8_t*)(Zh + m * 128 + c0) = h8;
      *(half8_t*)(Zl + m * 128 + c0) = l8;
    }
  }
  __syncthreads();

  int hsub = w >> 1, msub = w & 1;
  int mA = (msub << 5) + col;           // GEMM1: B row (m)
  int zrot = (mA & 15) << 3;
  int hrotA = (mA & 7) << 3;            // H store rotation
  int hrotB = (col & 7) << 3;           // H read rotation (rows col, col+32)

  for (int l = 0; l < 2; l++) {
    const f16* w1h = wsh + (size_t)((sm * 2 + l) * 256) * 128;
    const f16* w2h = wsh + 2 * NW1 + (size_t)((sm * 2 + l) * 128) * 256;
    f32x16 acc2[2];
#pragma unroll
    for (int i = 0; i < 16; i++) { acc2[0][i] = 0.f; acc2[1][i] = 0.f; }

#pragma unroll
    for (int hq = 0; hq < 4; hq++) {
      // ---- GEMM1: acc1 = H^T tile; A=W1 rows h, B=Z rows m ----
      f32x16 acc1;
#pragma unroll
      for (int i = 0; i < 16; i++) acc1[i] = 0.f;
      const f16* a1h = w1h + (size_t)((hq << 6) + (hsub << 5) + col) * 128 + (koct << 3);
      const f16* a1l = a1h + NW1;
#pragma unroll
      for (int kc = 0; kc < 8; kc++) {
        half8_t ah = *(const half8_t*)(a1h + (kc << 4));
        half8_t al = *(const half8_t*)(a1l + (kc << 4));
        int c = (((kc << 4) + (koct << 3)) + zrot) & 127;
        half8_t bh = *(const half8_t*)(Zh + mA * 128 + c);
        half8_t bl = *(const half8_t*)(Zl + mA * 128 + c);
        acc1 = mfma_f16(ah, bh, acc1);
        acc1 = mfma_f16(al, bh, acc1);
        acc1 = mfma_f16(ah, bl, acc1);
      }
      // epilogue1: relu, rescale (acc*2^-16*256), split, store H[mA][h_local]
#pragma unroll
      for (int qd = 0; qd < 4; qd++) {
        half4_t hv, lv;
#pragma unroll
        for (int j = 0; j < 4; j++) {
          float tv = fmaxf(acc1[(qd << 2) + j], 0.f) * 0.00390625f;
          f16 h = (f16)tv; hv[j] = h; lv[j] = (f16)(tv - (float)h);
        }
        int c = (((hsub << 5) + (qd << 3) + (koct << 2)) + hrotA) & 63;
        *(half4_t*)(Hh + (mA << 6) + c) = hv;
        *(half4_t*)(Hl + (mA << 6) + c) = lv;
      }
      __syncthreads();
      // ---- GEMM2 partial: A=W2 rows d=32w+col, B=H rows m (both tiles) ----
      const f16* a2h = w2h + (size_t)((w << 5) + col) * 256 + (hq << 6) + (koct << 3);
      const f16* a2l = a2h + NW1;
#pragma unroll
      for (int kc = 0; kc < 4; kc++) {
        half8_t ah = *(const half8_t*)(a2h + (kc << 4));
        half8_t al = *(const half8_t*)(a2l + (kc << 4));
        int c = (((kc << 4) + (koct << 3)) + hrotB) & 63;
        half8_t bh0 = *(const half8_t*)(Hh + (col << 6) + c);
        half8_t bl0 = *(const half8_t*)(Hl + (col << 6) + c);
        acc2[0] = mfma_f16(ah, bh0, acc2[0]);
        acc2[0] = mfma_f16(al, bh0, acc2[0]);
        acc2[0] = mfma_f16(ah, bl0, acc2[0]);
        half8_t bh1 = *(const half8_t*)(Hh + ((col + 32) << 6) + c);
        half8_t bl1 = *(const half8_t*)(Hl + ((col + 32) << 6) + c);
        acc2[1] = mfma_f16(ah, bh1, acc2[1]);
        acc2[1] = mfma_f16(al, bh1, acc2[1]);
        acc2[1] = mfma_f16(ah, bl1, acc2[1]);
      }
      __syncthreads();
    }
    // ---- epilogue2: Z[m][32w + d_local] += acc2 * 2^-8 (scaled units) ----
#pragma unroll
    for (int mt = 0; mt < 2; mt++) {
      int m = (mt << 5) + col;
      int rot = (m & 15) << 3;
      f16* zhr = Zh + m * 128;
      f16* zlr = Zl + m * 128;
#pragma unroll
      for (int qd = 0; qd < 4; qd++) {
        int c = (((w << 5) + (qd << 3) + (koct << 2)) + rot) & 127;
        half4_t zh = *(half4_t*)(zhr + c);
        half4_t zl = *(half4_t*)(zlr + c);
#pragma unroll
        for (int j = 0; j < 4; j++) {
          float zs = (float)zh[j] + (float)zl[j];
          zs += acc2[mt][(qd << 2) + j] * 0.00390625f;
          f16 h = (f16)zs; zh[j] = h; zl[j] = (f16)(zs - (float)h);
        }
        *(half4_t*)(zhr + c) = zh;
        *(half4_t*)(zlr + c) = zl;
      }
    }
    __syncthreads();
  }

  // ---- dist = ||rb - z||^2 over 64 rows (4 threads/row, 32 d each) ----
  float* pd = (float*)Hh;
  int* rwin = (int*)Hh + 64;
  {
    int row = tx >> 2, seg = tx & 3;
    int rot = (row & 15) << 3;
    const f16* zhr = Zh + row * 128;
    const f16* zlr = Zl + row * 128;
    const float* rb = ws + WS_RB + b * 128 + (seg << 5);
    float s = 0.f;
#pragma unroll
    for (int o = 0; o < 4; o++) {
      int c = (((seg << 5) + (o << 3)) + rot) & 127;
      half8_t zh = *(const half8_t*)(zhr + c);
      half8_t zl = *(const half8_t*)(zlr + c);
      float4 r0 = *(const float4*)(rb + (o << 3));
      float4 r1 = *(const float4*)(rb + (o << 3) + 4);
      float rr[8] = {r0.x, r0.y, r0.z, r0.w, r1.x, r1.y, r1.z, r1.w};
#pragma unroll
      for (int j = 0; j < 8; j++) {
        float z = ((float)zh[j] + (float)zl[j]) * 0.00390625f;
        float dlt = rr[j] - z;
        s += dlt * dlt;
      }
    }
    s += __shfl_xor(s, 1);   // all 4 lanes of a row end bit-identical
    s += __shfl_xor(s, 2);
    if (seg == 0) pd[row] = s;
  }
  __syncthreads();
  if (tx < 64) {
    float v = pd[tx]; int idx = tx;
#pragma unroll
    for (int off = 32; off; off >>= 1) {
      float v2 = __shfl_xor(v, off);
      int   i2 = __shfl_xor(idx, off);
      if (v2 < v || (v2 == v && i2 < idx)) { v = v2; idx = i2; }
    }
    if (tx == 0) {
      ws[WS_BESTD + (b << 2) + t] = v;
      ((int*)ws)[WS_BESTI + (b << 2) + t] = k0 + idx;
      rwin[0] = idx;
    }
  }
  __syncthreads();
  if (tx < 32) {
    int rw = rwin[0];
    int c = ((tx << 2) + ((rw & 15) << 3)) & 127;
    half4_t zh = *(const half4_t*)(Zh + rw * 128 + c);
    half4_t zl = *(const half4_t*)(Zl + rw * 128 + c);
    float4 z;
    z.x = ((float)zh[0] + (float)zl[0]) * 0.00390625f;
    z.y = ((float)zh[1] + (float)zl[1]) * 0.00390625f;
    z.z = ((float)zh[2] + (float)zl[2]) * 0.00390625f;
    z.w = ((float)zh[3] + (float)zl[3]) * 0.00390625f;
    *(float4*)(ws + WS_BESTZ + (((b << 2) + t) << 7) + (tx << 2)) = z;
  }
}

// ---------------- fallback k_step (round 7, on-the-fly split) ----------------
__device__ __forceinline__ void split8s(float4 p, float4 q, half8_t& hi, half8_t& lo) {
  float s[8] = {p.x, p.y, p.z, p.w, q.x, q.y, q.z, q.w};
#pragma unroll
  for (int i = 0; i < 8; i++) {
    float v = s[i] * 256.f;
    f16 h = (f16)v;
    hi[i] = h;
    lo[i] = (f16)(v - (float)h);
  }
}
__device__ __forceinline__ half8_t ldsB(const f16* base, int m, int d0) {
  int rot = (m & 15) << 2;
  const f16* r = base + m * 128;
  half4_t a = *(const half4_t*)(r + ((d0 + rot) & 127));
  half4_t b = *(const half4_t*)(r + ((d0 + 4 + rot) & 127));
  return __builtin_shufflevector(a, b, 0, 1, 2, 3, 4, 5, 6, 7);
}
__global__ __launch_bounds__(256, 2) void k_step_fb(const float* __restrict__ W1g,
    const float* __restrict__ W2g, float* __restrict__ ws, int sm)
{
  __shared__ f16 Zh[8192];
  __shared__ f16 Zl[8192];
  __shared__ f16 Hh[8192];
  __shared__ f16 Hl[8192];
  int tx = threadIdx.x;
  int lane = tx & 63, w = tx >> 6;
  int col = lane & 31, koct = lane >> 5;
  int b = blockIdx.x >> 2, t = blockIdx.x & 3, k0 = t << 6;
  {
    const float* zc = ws + WS_ZC + k0 * 128;
    const float* y  = ws + WS_Y + b * 128;
    for (int idx = tx; idx < 1024; idx += 256) {
      int m = idx & 63, d0 = (idx >> 6) << 3;
      float4 a  = *(const float4*)(zc + m * 128 + d0);
      float4 bb = *(const float4*)(zc + m * 128 + d0 + 4);
      float4 ya = *(const float4*)(y + d0);
      float4 yb = *(const float4*)(y + d0 + 4);
      float sv[8] = {a.x + ya.x, a.y + ya.y, a.z + ya.z, a.w + ya.w,
                     bb.x + yb.x, bb.y + yb.y, bb.z + yb.z, bb.w + yb.w};
      int rot = (m & 15) << 2;
      int c0 = (d0 + rot) & 127, c1 = (d0 + 4 + rot) & 127;
      half4_t h0, l0, h1, l1;
#pragma unroll
      for (int j = 0; j < 4; j++) {
        float v = sv[j] * 256.f;
        f16 h = (f16)v; h0[j] = h; l0[j] = (f16)(v - (float)h);
        v = sv[j + 4] * 256.f;
        h = (f16)v; h1[j] = h; l1[j] = (f16)(v - (float)h);
      }
      *(half4_t*)(Zh + m * 128 + c0) = h0;
      *(half4_t*)(Zl + m * 128 + c0) = l0;
      *(half4_t*)(Zh + m * 128 + c1) = h1;
      *(half4_t*)(Zl + m * 128 + c1) = l1;
    }
  }
  __syncthreads();
  for (int l = 0; l < 2; l++) {
    const float* w1l = W1g + (size_t)(sm * 2 + l) * (256 * 128);
    const float* w2l = W2g + (size_t)(sm * 2 + l) * (128 * 256);
    f32x16 acc2[2];
#pragma unroll
    for (int i = 0; i < 16; i++) { acc2[0][i] = 0.f; acc2[1][i] = 0.f; }
#pragma unroll
    for (int hf = 0; hf < 2; hf++) {
      f32x16 acc1[2];
#pragma unroll
      for (int i = 0; i < 16; i++) { acc1[0][i] = 0.f; acc1[1][i] = 0.f; }
      const float* w1base = w1l + (size_t)(hf * 128 + (w << 5) + col) * 128 + (koct << 3);
#pragma unroll
      for (int kc = 0; kc < 8; kc++) {
        int d0 = kc << 4;
        float4 p = *(const float4*)(w1base + d0);
        float4 q = *(const float4*)(w1base + d0 + 4);
        half8_t ah, al; split8s(p, q, ah, al);
        int dd = d0 + (koct << 3);
        half8_t bh0 = ldsB(Zh, col, dd);
        half8_t bl0 = ldsB(Zl, col, dd);
        acc1[0] = mfma_f16(ah, bh0, acc1[0]);
        acc1[0] = mfma_f16(al, bh0, acc1[0]);
        acc1[0] = mfma_f16(ah, bl0, acc1[0]);
        half8_t bh1 = ldsB(Zh, col + 32, dd);
        half8_t bl1 = ldsB(Zl, col + 32, dd);
        acc1[1] = mfma_f16(ah, bh1, acc1[1]);
        acc1[1] = mfma_f16(al, bh1, acc1[1]);
        acc1[1] = mfma_f16(ah, bl1, acc1[1]);
      }
#pragma unroll
      for (int mt = 0; mt < 2; mt++) {
        int mrow = (mt << 5) + col;
        int rot = (mrow & 15) << 2;
        f16* hhr = Hh + mrow * 128;
        f16* hlr = Hl + mrow * 128;
#pragma unroll
        for (int qd = 0; qd < 4; qd++) {
          half4_t hv, lv;
#pragma unroll
          for (int j = 0; j < 4; j++) {
            float tv = fmaxf(acc1[mt][(qd << 2) + j], 0.f) * 0.00390625f;
            f16 h = (f16)tv; hv[j] = h; lv[j] = (f16)(tv - (float)h);
          }
          int c = (((w << 5) + (qd << 3) + (koct << 2)) + rot) & 127;
          *(half4_t*)(hhr + c) = hv;
          *(half4_t*)(hlr + c) = lv;
        }
      }
      __syncthreads();
      const float* w2base = w2l + (size_t)((w << 5) + col) * 256 + hf * 128 + (koct << 3);
#pragma unroll
      for (int kc = 0; kc < 8; kc++) {
        int h0 = kc << 4;
        float4 p = *(const float4*)(w2base + h0);
        float4 q = *(const float4*)(w2base + h0 + 4);
        half8_t ah, al; split8s(p, q, ah, al);
        int hh0 = h0 + (koct << 3);
        half8_t bh0 = ldsB(Hh, col, hh0);
        half8_t bl0 = ldsB(Hl, col, hh0);
        acc2[0] = mfma_f16(ah, bh0, acc2[0]);
        acc2[0] = mfma_f16(al, bh0, acc2[0]);
        acc2[0] = mfma_f16(ah, bl0, acc2[0]);
        half8_t bh1 = ldsB(Hh, col + 32, hh0);
        half8_t bl1 = ldsB(Hl, col + 32, hh0);
        acc2[1] = mfma_f16(ah, bh1, acc2[1]);
        acc2[1] = mfma_f16(al, bh1, acc2[1]);
        acc2[1] = mfma_f16(ah, bl1, acc2[1]);
      }
      __syncthreads();
    }
#pragma unroll
    for (int mt = 0; mt < 2; mt++) {
      int mrow = (mt << 5) + col;
      int rot = (mrow & 15) << 2;
      f16* zhr = Zh + mrow * 128;
      f16* zlr = Zl + mrow * 128;
#pragma unroll
      for (int qd = 0; qd < 4; qd++) {
        int c = (((w << 5) + (qd << 3) + (koct << 2)) + rot) & 127;
        half4_t zh = *(half4_t*)(zhr + c);
        half4_t zl = *(half4_t*)(zlr + c);
#pragma unroll
        for (int j = 0; j < 4; j++) {
          float zs = (float)zh[j] + (float)zl[j];
          zs += acc2[mt][(qd << 2) + j] * 0.00390625f;
          f16 h = (f16)zs; zh[j] = h; zl[j] = (f16)(zs - (float)h);
        }
        *(half4_t*)(zhr + c) = zh;
        *(half4_t*)(zlr + c) = zl;
      }
    }
    __syncthreads();
  }
  float* pd = (float*)Hh;
  int* rwin = (int*)Hh + 64;
  {
    int row = tx >> 2, seg = tx & 3;
    const float* rb = ws + WS_RB + b * 128 + (seg << 5);
    int rot = (row & 15) << 2;
    const f16* zhr = Zh + row * 128;
    const f16* zlr = Zl + row * 128;
    float s = 0.f;
#pragma unroll
    for (int o = 0; o < 4; o++) {
      int d = (seg << 5) + (o << 3);
      int c0 = (d + rot) & 127, c1 = (d + 4 + rot) & 127;
      half4_t zh0 = *(const half4_t*)(zhr + c0);
      half4_t zl0 = *(const half4_t*)(zlr + c0);
      half4_t zh1 = *(const half4_t*)(zhr + c1);
      half4_t zl1 = *(const half4_t*)(zlr + c1);
      float4 r0 = *(const float4*)(rb + (o << 3));
      float4 r1 = *(const float4*)(rb + (o << 3) + 4);
      float z, dlt;
      z = ((float)zh0[0] + (float)zl0[0]) * 0.00390625f; dlt = r0.x - z; s += dlt * dlt;
      z = ((float)zh0[1] + (float)zl0[1]) * 0.00390625f; dlt = r0.y - z; s += dlt * dlt;
      z = ((float)zh0[2] + (float)zl0[2]) * 0.00390625f; dlt = r0.z - z; s += dlt * dlt;
      z = ((float)zh0[3] + (float)zl0[3]) * 0.00390625f; dlt = r0.w - z; s += dlt * dlt;
      z = ((float)zh1[0] + (float)zl1[0]) * 0.00390625f; dlt = r1.x - z; s += dlt * dlt;
      z = ((float)zh1[1] + (float)zl1[1]) * 0.00390625f; dlt = r1.y - z; s += dlt * dlt;
      z = ((float)zh1[2] + (float)zl1[2]) * 0.00390625f; dlt = r1.z - z; s += dlt * dlt;
      z = ((float)zh1[3] + (float)zl1[3]) * 0.00390625f; dlt = r1.w - z; s += dlt * dlt;
    }
    s += __shfl_xor(s, 1);
    s += __shfl_xor(s, 2);
    if (seg == 0) pd[row] = s;
  }
  __syncthreads();
  if (tx < 64) {
    float v = pd[tx]; int idx = tx;
#pragma unroll
    for (int off = 32; off; off >>= 1) {
      float v2 = __shfl_xor(v, off);
      int   i2 = __shfl_xor(idx, off);
      if (v2 < v || (v2 == v && i2 < idx)) { v = v2; idx = i2; }
    }
    if (tx == 0) {
      ws[WS_BESTD + (b << 2) + t] = v;
      ((int*)ws)[WS_BESTI + (b << 2) + t] = k0 + idx;
      rwin[0] = idx;
    }
  }
  __syncthreads();
  if (tx < 32) {
    int rw = rwin[0];
    int c = ((tx << 2) + ((rw & 15) << 2)) & 127;
    half4_t zh = *(const half4_t*)(Zh + rw * 128 + c);
    half4_t zl = *(const half4_t*)(Zl + rw * 128 + c);
    float4 z;
    z.x = ((float)zh[0] + (float)zl[0]) * 0.00390625f;
    z.y = ((float)zh[1] + (float)zl[1]) * 0.00390625f;
    z.z = ((float)zh[2] + (float)zl[2]) * 0.00390625f;
    z.w = ((float)zh[3] + (float)zl[3]) * 0.00390625f;
    *(float4*)(ws + WS_BESTZ + (((b << 2) + t) << 7) + (tx << 2)) = z;
  }
}

// ---------------- per-step update: pick tile winner, advance xhat ----------------
__global__ __launch_bounds__(128) void k_update(const float* __restrict__ x,
    float* __restrict__ ws, float* __restrict__ out, int m, int last)
{
  __shared__ int tsel;
  int tx = threadIdx.x, b = blockIdx.x;
  if (tx == 0) {
    float bv = ws[WS_BESTD + (b << 2)]; int bt = 0;
    for (int q = 1; q < 4; q++) {
      float v = ws[WS_BESTD + (b << 2) + q];
      if (v < bv) { bv = v; bt = q; }     // strict <: ties -> lowest k (tile order)
    }
    tsel = bt;
    int k = ((const int*)ws)[WS_BESTI + (b << 2) + bt];
    out[OUT_CODES + b * 8 + (m + 1)] = (float)k;
  }
  __syncthreads();
  int bt = tsel;
  float z  = ws[WS_BESTZ + (((b << 2) + bt) << 7) + tx];
  float xh = ws[WS_XHAT + b * 128 + tx] + z;
  ws[WS_XHAT + b * 128 + tx] = xh;
  ws[WS_RB   + b * 128 + tx] = x[b * 128 + tx] - xh;
  out[OUT_SIDE + (m + 1) * 131072 + b * 128 + tx] = xh;
  if (last) out[b * 128 + tx] = xh;       // final xhat == side[7]
}

extern "C" void kernel_launch(void* const* d_in, const int* in_sizes, int n_in,
                              void* d_out, int out_size, void* d_ws, size_t ws_size,
                              hipStream_t stream)
{
  const float* x   = (const float*)d_in[0];
  const float* cb0 = (const float*)d_in[1];
  const float* cbs = (const float*)d_in[2];
  const float* Wc  = (const float*)d_in[3];
  const float* bc  = (const float*)d_in[4];
  const float* W1  = (const float*)d_in[5];
  const float* W2  = (const float*)d_in[6];
  float* out = (float*)d_out;
  float* ws  = (float*)d_ws;
  f16* wsh = (f16*)(ws + WS_WSPLIT);
  const bool pre = ws_size >= (size_t)WS_NEED_BYTES;

  if (pre) k_wsplit<<<896, 256, 0, stream>>>(W1, W2, wsh);
  k_step0<<<1024, 256, 0, stream>>>(x, cb0, ws, out);
  for (int m = 0; m < 7; m++) {
    k_prep<<<1280, 128, 0, stream>>>(cbs + m * 256 * 128, Wc + m * 128 * 256,
                                     bc + m * 128, ws);
    if (pre) k_step<<<4096, 256, 0, stream>>>(wsh, ws, m);
    else     k_step_fb<<<4096, 256, 0, stream>>>(W1, W2, ws, m);
    k_update<<<1024, 128, 0, stream>>>(x, ws, out, m, (m == 6) ? 1 : 0);
  }
}

// Round 10
// 2137.576 us; speedup vs baseline: 1.3893x; 1.3893x over previous
//
#include <hip/hip_runtime.h>

// QINCo round 10: R9 structure made launch-legal.
//  - Single 64KB LDS block (32768 halfs) with compile-time offsets:
//    Zh=+0, Zl=+8192, Hh=+16384, Hl=+24576. hi->lo = constant 8192.
//  - Rotation-by-8 layout (no padding): element (m,d) at (d+8*(m&15))&127.
//    All hot LDS ops are single aligned b128/b64; pattern is bank-balanced.
//  - Pre-split fp16 hi/lo weights (k_wsplit), A-fragments preloaded to regs,
//    2 independent MFMA chains per GEMM, 4 barriers/layer.
// Shapes: D=128, M=8, K=256, L=2, H=256, BS=1024.
// Out layout (floats): xhat[1024*128] | codes[1024*8] | side[8][1024*128]

typedef _Float16 f16;
typedef f16 half4_t __attribute__((ext_vector_type(4)));
typedef f16 half8_t __attribute__((ext_vector_type(8)));
typedef float f32x16 __attribute__((ext_vector_type(16)));

#define OUT_CODES 131072
#define OUT_SIDE  139264

// ws float offsets
#define WS_XHAT  0          // [1024][128]
#define WS_RB    131072     // [1024][128]  r = x - xhat
#define WS_Y     262144     // [1024][128]  y = xhat @ Wx^T
#define WS_ZC    393216     // [256][128]   zc = cb + cb@Wz^T + bc
#define WS_BESTD 425984     // [1024][4]
#define WS_BESTI 430080     // [1024][4] (int)
#define WS_BESTZ 434176     // [1024][4][128]
#define WS_WSPLIT 960000    // f16 region: W1H|W1L|W2H|W2L, NW1 halfs each
#define NW1 458752          // 7*2*256*128

#define HLO 8192            // hi->lo LDS offset (halfs), compile-time

__device__ __forceinline__ f32x16 mfma_f16(half8_t a, half8_t b, f32x16 c) {
  return __builtin_amdgcn_mfma_f32_32x32x16_f16(a, b, c, 0, 0, 0);
}

// ---------------- weight pre-split: fp32 -> scaled (x256) fp16 hi/lo ----------------
__global__ __launch_bounds__(256) void k_wsplit(const float* __restrict__ W1,
    const float* __restrict__ W2, f16* __restrict__ wsh)
{
  int i = (blockIdx.x * 256 + threadIdx.x) * 4;      // [0, 2*NW1)
  const float* src;
  f16* hi;
  if (i < NW1) { src = W1 + i; hi = wsh + i; }
  else         { src = W2 + (i - NW1); hi = wsh + 2 * NW1 + (i - NW1); }
  f16* lo = hi + NW1;
  float4 v = *(const float4*)src;
  half4_t h, l;
  float s;
  s = v.x * 256.f; h[0] = (f16)s; l[0] = (f16)(s - (float)h[0]);
  s = v.y * 256.f; h[1] = (f16)s; l[1] = (f16)(s - (float)h[1]);
  s = v.z * 256.f; h[2] = (f16)s; l[2] = (f16)(s - (float)h[2]);
  s = v.w * 256.f; h[3] = (f16)s; l[3] = (f16)(s - (float)h[3]);
  *(half4_t*)hi = h;
  *(half4_t*)lo = l;
}

// ---------------- step 0: nearest codebook0 row ----------------
__global__ __launch_bounds__(256) void k_step0(const float* __restrict__ x,
    const float* __restrict__ cb0, float* __restrict__ ws, float* __restrict__ out)
{
  __shared__ float xs[128];
  __shared__ float redv[4];
  __shared__ int   redi[4];
  __shared__ int   kwin;
  int tx = threadIdx.x, b = blockIdx.x;
  if (tx < 128) xs[tx] = x[b * 128 + tx];
  __syncthreads();
  const float* c = cb0 + tx * 128;   // k = tx
  float s = 0.f;
  for (int d = 0; d < 128; d += 4) {
    float4 cv = *(const float4*)(c + d);
    float4 xv = *(const float4*)(xs + d);
    float a0 = xv.x - cv.x, a1 = xv.y - cv.y, a2 = xv.z - cv.z, a3 = xv.w - cv.w;
    s += a0 * a0 + a1 * a1 + a2 * a2 + a3 * a3;
  }
  float v = s; int idx = tx;
  for (int off = 32; off; off >>= 1) {
    float v2 = __shfl_xor(v, off);
    int   i2 = __shfl_xor(idx, off);
    if (v2 < v || (v2 == v && i2 < idx)) { v = v2; idx = i2; }
  }
  if ((tx & 63) == 0) { redv[tx >> 6] = v; redi[tx >> 6] = idx; }
  __syncthreads();
  if (tx == 0) {
    float bv = redv[0]; int bi = redi[0];
    for (int w = 1; w < 4; w++)
      if (redv[w] < bv || (redv[w] == bv && redi[w] < bi)) { bv = redv[w]; bi = redi[w]; }
    kwin = bi;
    out[OUT_CODES + b * 8] = (float)bi;
  }
  __syncthreads();
  int k = kwin;
  if (tx < 128) {
    float xh = cb0[k * 128 + tx];
    ws[WS_XHAT + b * 128 + tx] = xh;
    ws[WS_RB   + b * 128 + tx] = xs[tx] - xh;
    out[OUT_SIDE + b * 128 + tx] = xh;   // side[0]
  }
}

// ---------------- per-step prep: zc and y (fp32) ----------------
__global__ __launch_bounds__(128) void k_prep(const float* __restrict__ cb,
    const float* __restrict__ Wc, const float* __restrict__ bcm, float* __restrict__ ws)
{
  __shared__ float row[128];
  int tx = threadIdx.x, blk = blockIdx.x;
  if (blk < 256) {          // zc[k][i] = cb[k][i] + sum_d cb[k][d]*Wc[i][d] + bc[i]
    row[tx] = cb[blk * 128 + tx];
    __syncthreads();
    const float* wrow = Wc + tx * 256;
    float s = 0.f;
    for (int d = 0; d < 128; d += 4) {
      float4 wv = *(const float4*)(wrow + d);
      float4 zv = *(const float4*)(row + d);
      s += wv.x * zv.x + wv.y * zv.y + wv.z * zv.z + wv.w * zv.w;
    }
    ws[WS_ZC + blk * 128 + tx] = row[tx] + s + bcm[tx];
  } else {                  // y[b][i] = sum_d xhat[b][d]*Wc[i][128+d]
    int b = blk - 256;
    row[tx] = ws[WS_XHAT + b * 128 + tx];
    __syncthreads();
    const float* wrow = Wc + tx * 256 + 128;
    float s = 0.f;
    for (int d = 0; d < 128; d += 4) {
      float4 wv = *(const float4*)(wrow + d);
      float4 zv = *(const float4*)(row + d);
      s += wv.x * zv.x + wv.y * zv.y + wv.z * zv.z + wv.w * zv.w;
    }
    ws[WS_Y + b * 128 + tx] = s;
  }
}

// ---------------- main step kernel ----------------
// 256 threads = 4 waves. lane: col = lane&31, koct = lane>>5.
// LDS rows 128 halfs; logical d of row m at phys (d + 8*(m&15)) & 127.
// GEMM1 per hf: wave w -> H^T rows h = hf*128 + 32w + col (A=W1 pre-split),
//   B = Z m-tiles (rows col / col+32 — same rotation), 2 chains acc1[2].
// GEMM2 per hf: wave w -> d rows 32w+col (A=W2 pre-split), B = H m-tiles,
//   2 chains acc2[2] accumulated across hf.
// C/D layout: col(lane&31) = N index (m); row M = (reg&3)+8*(reg>>2)+4*koct.
__global__ __launch_bounds__(256, 2) void k_step(const f16* __restrict__ wsh,
    float* __restrict__ ws, int sm)
{
  __shared__ __align__(16) f16 lds[32768];     // 64 KB exactly
  f16* Zh = lds;            // [64][128]
  f16* Zl = lds + HLO;
  f16* Hh = lds + 2 * HLO;
  f16* Hl = lds + 3 * HLO;  // Hl - Hh == Zl - Zh == HLO by construction
  int tx = threadIdx.x;
  int lane = tx & 63, w = tx >> 6;
  int col = lane & 31, koct = lane >> 5;
  int b = blockIdx.x >> 2, t = blockIdx.x & 3, k0 = t << 6;

  // ---- init Z = zc[k0+m] + y[b], split x256 into Zh/Zl (rotated store) ----
  {
    const float* zc = ws + WS_ZC + k0 * 128;
    const float* y  = ws + WS_Y + b * 128;
    for (int idx = tx; idx < 1024; idx += 256) {
      int m = idx & 63, d0 = (idx >> 6) << 3;
      float4 a  = *(const float4*)(zc + m * 128 + d0);
      float4 bb = *(const float4*)(zc + m * 128 + d0 + 4);
      float4 ya = *(const float4*)(y + d0);
      float4 yb = *(const float4*)(y + d0 + 4);
      float sv[8] = {a.x + ya.x, a.y + ya.y, a.z + ya.z, a.w + ya.w,
                     bb.x + yb.x, bb.y + yb.y, bb.z + yb.z, bb.w + yb.w};
      half8_t h8, l8;
#pragma unroll
      for (int j = 0; j < 8; j++) {
        float v = sv[j] * 256.f;
        f16 h = (f16)v; h8[j] = h; l8[j] = (f16)(v - (float)h);
      }
      int c0 = (d0 + ((m & 15) << 3)) & 127;
      *(half8_t*)(Zh + (m << 7) + c0) = h8;
      *(half8_t*)(Zl + (m << 7) + c0) = l8;
    }
  }
  __syncthreads();

  const int rot0 = (col & 15) << 3;        // rotation for rows col and col+32
  const f16* Zr0 = Zh + (col << 7);
  const f16* Zr1 = Zh + ((col + 32) << 7);
  const f16* Hr0 = Hh + (col << 7);
  const f16* Hr1 = Hh + ((col + 32) << 7);

  for (int l = 0; l < 2; l++) {
    const f16* w1h = wsh + (size_t)((sm * 2 + l) * 256) * 128;
    const f16* w2h = wsh + 2 * NW1 + (size_t)((sm * 2 + l) * 128) * 256;
    f32x16 acc2[2];
#pragma unroll
    for (int i = 0; i < 16; i++) { acc2[0][i] = 0.f; acc2[1][i] = 0.f; }

#pragma unroll
    for (int hf = 0; hf < 2; hf++) {
      // ---- preload A fragments (GEMM1 then GEMM2) ----
      const f16* a1p = w1h + (size_t)((hf << 7) + (w << 5) + col) * 128 + (koct << 3);
      const f16* a2p = w2h + (size_t)((w << 5) + col) * 256 + (hf << 7) + (koct << 3);
      half8_t a1hv[8], a1lv[8], a2hv[8], a2lv[8];
#pragma unroll
      for (int kc = 0; kc < 8; kc++) {
        a1hv[kc] = *(const half8_t*)(a1p + (kc << 4));
        a1lv[kc] = *(const half8_t*)(a1p + NW1 + (kc << 4));
      }
#pragma unroll
      for (int kc = 0; kc < 8; kc++) {
        a2hv[kc] = *(const half8_t*)(a2p + (kc << 4));
        a2lv[kc] = *(const half8_t*)(a2p + NW1 + (kc << 4));
      }

      // ---- GEMM1: 2 chains (m-tiles), pure LDS + MFMA ----
      f32x16 acc1[2];
#pragma unroll
      for (int i = 0; i < 16; i++) { acc1[0][i] = 0.f; acc1[1][i] = 0.f; }
#pragma unroll
      for (int kc = 0; kc < 8; kc++) {
        int poff = (((kc << 4) + (koct << 3)) + rot0) & 127;
        half8_t bh0 = *(const half8_t*)(Zr0 + poff);
        half8_t bl0 = *(const half8_t*)(Zr0 + HLO + poff);
        half8_t bh1 = *(const half8_t*)(Zr1 + poff);
        half8_t bl1 = *(const half8_t*)(Zr1 + HLO + poff);
        acc1[0] = mfma_f16(a1hv[kc], bh0, acc1[0]);
        acc1[1] = mfma_f16(a1hv[kc], bh1, acc1[1]);
        acc1[0] = mfma_f16(a1lv[kc], bh0, acc1[0]);
        acc1[1] = mfma_f16(a1lv[kc], bh1, acc1[1]);
        acc1[0] = mfma_f16(a1hv[kc], bl0, acc1[0]);
        acc1[1] = mfma_f16(a1hv[kc], bl1, acc1[1]);
      }
      // epilogue1: relu, rescale (x 2^-8), split, store H[m][h_local]
#pragma unroll
      for (int mt = 0; mt < 2; mt++) {
        int m = (mt << 5) + col;
#pragma unroll
        for (int qd = 0; qd < 4; qd++) {
          half4_t hv, lv;
#pragma unroll
          for (int j = 0; j < 4; j++) {
            float tv = fmaxf(acc1[mt][(qd << 2) + j], 0.f) * 0.00390625f;
            f16 h = (f16)tv; hv[j] = h; lv[j] = (f16)(tv - (float)h);
          }
          int c = (((w << 5) + (qd << 3) + (koct << 2)) + rot0) & 127;
          *(half4_t*)(Hh + (m << 7) + c) = hv;
          *(half4_t*)(Hl + (m << 7) + c) = lv;
        }
      }
      __syncthreads();
      // ---- GEMM2 partial: 2 chains, pure LDS + MFMA ----
#pragma unroll
      for (int kc = 0; kc < 8; kc++) {
        int poff = (((kc << 4) + (koct << 3)) + rot0) & 127;
        half8_t bh0 = *(const half8_t*)(Hr0 + poff);
        half8_t bl0 = *(const half8_t*)(Hr0 + HLO + poff);
        half8_t bh1 = *(const half8_t*)(Hr1 + poff);
        half8_t bl1 = *(const half8_t*)(Hr1 + HLO + poff);
        acc2[0] = mfma_f16(a2hv[kc], bh0, acc2[0]);
        acc2[1] = mfma_f16(a2hv[kc], bh1, acc2[1]);
        acc2[0] = mfma_f16(a2lv[kc], bh0, acc2[0]);
        acc2[1] = mfma_f16(a2lv[kc], bh1, acc2[1]);
        acc2[0] = mfma_f16(a2hv[kc], bl0, acc2[0]);
        acc2[1] = mfma_f16(a2hv[kc], bl1, acc2[1]);
      }
      __syncthreads();
    }
    // ---- epilogue2: Z[m][32w + d_local] += acc2 * 2^-8 (scaled units) ----
#pragma unroll
    for (int mt = 0; mt < 2; mt++) {
      int m = (mt << 5) + col;
      f16* zhr = Zh + (m << 7);
      f16* zlr = Zl + (m << 7);
#pragma unroll
      for (int qd = 0; qd < 4; qd++) {
        int c = (((w << 5) + (qd << 3) + (koct << 2)) + rot0) & 127;
        half4_t zh = *(half4_t*)(zhr + c);
        half4_t zl = *(half4_t*)(zlr + c);
#pragma unroll
        for (int j = 0; j < 4; j++) {
          float zs = (float)zh[j] + (float)zl[j];
          zs += acc2[mt][(qd << 2) + j] * 0.00390625f;
          f16 h = (f16)zs; zh[j] = h; zl[j] = (f16)(zs - (float)h);
        }
        *(half4_t*)(zhr + c) = zh;
        *(half4_t*)(zlr + c) = zl;
      }
    }
    __syncthreads();
  }

  // ---- dist = ||rb - z||^2 over 64 rows (4 threads/row, 32 d each) ----
  float* pd = (float*)Hh;
  int* rwin = (int*)Hh + 64;
  {
    int row = tx >> 2, seg = tx & 3;
    int rotr = (row & 15) << 3;
    const f16* zhr = Zh + (row << 7);
    const f16* zlr = Zl + (row << 7);
    const float* rb = ws + WS_RB + b * 128 + (seg << 5);
    float s = 0.f;
#pragma unroll
    for (int o = 0; o < 4; o++) {
      int c = (((seg << 5) + (o << 3)) + rotr) & 127;
      half8_t zh = *(const half8_t*)(zhr + c);
      half8_t zl = *(const half8_t*)(zlr + c);
      float4 r0 = *(const float4*)(rb + (o << 3));
      float4 r1 = *(const float4*)(rb + (o << 3) + 4);
      float rr[8] = {r0.x, r0.y, r0.z, r0.w, r1.x, r1.y, r1.z, r1.w};
#pragma unroll
      for (int j = 0; j < 8; j++) {
        float z = ((float)zh[j] + (float)zl[j]) * 0.00390625f;
        float dlt = rr[j] - z;
        s += dlt * dlt;
      }
    }
    s += __shfl_xor(s, 1);   // all 4 lanes of a row end bit-identical
    s += __shfl_xor(s, 2);
    if (seg == 0) pd[row] = s;
  }
  __syncthreads();
  if (tx < 64) {
    float v = pd[tx]; int idx = tx;
#pragma unroll
    for (int off = 32; off; off >>= 1) {
      float v2 = __shfl_xor(v, off);
      int   i2 = __shfl_xor(idx, off);
      if (v2 < v || (v2 == v && i2 < idx)) { v = v2; idx = i2; }
    }
    if (tx == 0) {
      ws[WS_BESTD + (b << 2) + t] = v;
      ((int*)ws)[WS_BESTI + (b << 2) + t] = k0 + idx;
      rwin[0] = idx;
    }
  }
  __syncthreads();
  if (tx < 32) {
    int rw = rwin[0];
    int c = ((tx << 2) + ((rw & 15) << 3)) & 127;
    half4_t zh = *(const half4_t*)(Zh + (rw << 7) + c);
    half4_t zl = *(const half4_t*)(Zl + (rw << 7) + c);
    float4 z;
    z.x = ((float)zh[0] + (float)zl[0]) * 0.00390625f;
    z.y = ((float)zh[1] + (float)zl[1]) * 0.00390625f;
    z.z = ((float)zh[2] + (float)zl[2]) * 0.00390625f;
    z.w = ((float)zh[3] + (float)zl[3]) * 0.00390625f;
    *(float4*)(ws + WS_BESTZ + (((b << 2) + t) << 7) + (tx << 2)) = z;
  }
}

// ---------------- per-step update: pick tile winner, advance xhat ----------------
__global__ __launch_bounds__(128) void k_update(const float* __restrict__ x,
    float* __restrict__ ws, float* __restrict__ out, int m, int last)
{
  __shared__ int tsel;
  int tx = threadIdx.x, b = blockIdx.x;
  if (tx == 0) {
    float bv = ws[WS_BESTD + (b << 2)]; int bt = 0;
    for (int q = 1; q < 4; q++) {
      float v = ws[WS_BESTD + (b << 2) + q];
      if (v < bv) { bv = v; bt = q; }     // strict <: ties -> lowest k (tile order)
    }
    tsel = bt;
    int k = ((const int*)ws)[WS_BESTI + (b << 2) + bt];
    out[OUT_CODES + b * 8 + (m + 1)] = (float)k;
  }
  __syncthreads();
  int bt = tsel;
  float z  = ws[WS_BESTZ + (((b << 2) + bt) << 7) + tx];
  float xh = ws[WS_XHAT + b * 128 + tx] + z;
  ws[WS_XHAT + b * 128 + tx] = xh;
  ws[WS_RB   + b * 128 + tx] = x[b * 128 + tx] - xh;
  out[OUT_SIDE + (m + 1) * 131072 + b * 128 + tx] = xh;
  if (last) out[b * 128 + tx] = xh;       // final xhat == side[7]
}

extern "C" void kernel_launch(void* const* d_in, const int* in_sizes, int n_in,
                              void* d_out, int out_size, void* d_ws, size_t ws_size,
                              hipStream_t stream)
{
  const float* x   = (const float*)d_in[0];
  const float* cb0 = (const float*)d_in[1];
  const float* cbs = (const float*)d_in[2];
  const float* Wc  = (const float*)d_in[3];
  const float* bc  = (const float*)d_in[4];
  const float* W1  = (const float*)d_in[5];
  const float* W2  = (const float*)d_in[6];
  float* out = (float*)d_out;
  float* ws  = (float*)d_ws;
  f16* wsh = (f16*)(ws + WS_WSPLIT);

  k_wsplit<<<896, 256, 0, stream>>>(W1, W2, wsh);
  k_step0<<<1024, 256, 0, stream>>>(x, cb0, ws, out);
  for (int m = 0; m < 7; m++) {
    k_prep<<<1280, 128, 0, stream>>>(cbs + m * 256 * 128, Wc + m * 128 * 256,
                                     bc + m * 128, ws);
    k_step<<<4096, 256, 0, stream>>>(wsh, ws, m);
    k_update<<<1024, 128, 0, stream>>>(x, ws, out, m, (m == 6) ? 1 : 0);
  }
}